// Round 5
// baseline (1728.526 us; speedup 1.0000x reference)
//
#include <hip/hip_runtime.h>

// Problem constants (B=2, N=1000, D=6, L=12, C=32, K=16, H=8)
#define NB 2
#define NN 1000
#define ND 6
#define NK 16
#define NH 8
#define DM 384        // L*C
#define MROWS 12000   // B*N*D
#define NTOK 2000     // B*N
#define NS 96         // K*D

typedef unsigned short u16;
typedef __attribute__((ext_vector_type(8))) short bf16x8;   // 8 bf16 (4 VGPRs)
typedef __attribute__((ext_vector_type(4))) float f32x4;

static __device__ __forceinline__ float4 ld4(const float* p){ return *reinterpret_cast<const float4*>(p); }
static __device__ __forceinline__ void st4(float* p, float4 v){ *reinterpret_cast<float4*>(p) = v; }

#define SCALE 0.14433756729740646f   // 1/sqrt(48)
#define GELU_K 0.70710678118654752f  // 1/sqrt(2)

// bf16 round-to-nearest-even of fp32, as raw u16
static __device__ __forceinline__ u16 bf_hi(float a){
    unsigned u = __float_as_uint(a);
    unsigned r = u + 0x7fffu + ((u >> 16) & 1u);
    return (u16)(r >> 16);
}
static __device__ __forceinline__ void bf_split(float a, u16& h, u16& l){
    h = bf_hi(a);
    const float hf = __uint_as_float(((unsigned)h) << 16);
    l = bf_hi(a - hf);
}

// ---------------------------------------------------------------------------
// Kernel 0: convert x -> xh/xl (row-major bf16 hi/lo) and Wq/Wk/Wv/Wo ->
// transposed [n][k] bf16 hi/lo.
// ---------------------------------------------------------------------------
#define NX4 1152000   // x float4 chunks  (12000*384/4)
#define NW4 36864     // per-weight float4 chunks (384*384/4)
__global__ __launch_bounds__(256)
void k_convert(const float* __restrict__ x,
               const float* __restrict__ Wq, const float* __restrict__ Wk,
               const float* __restrict__ Wv, const float* __restrict__ Wo,
               u16* __restrict__ xh, u16* __restrict__ xl,
               u16* __restrict__ Wth, u16* __restrict__ Wtl)
{
    const int idx = blockIdx.x * 256 + threadIdx.x;
    if (idx < NX4) {
        const float4 v = ld4(&x[(size_t)idx*4]);
        u16 h0,l0,h1,l1,h2,l2,h3,l3;
        bf_split(v.x,h0,l0); bf_split(v.y,h1,l1); bf_split(v.z,h2,l2); bf_split(v.w,h3,l3);
        ushort4 vh; vh.x=h0; vh.y=h1; vh.z=h2; vh.w=h3;
        ushort4 vl; vl.x=l0; vl.y=l1; vl.z=l2; vl.w=l3;
        *reinterpret_cast<ushort4*>(&xh[(size_t)idx*4]) = vh;
        *reinterpret_cast<ushort4*>(&xl[(size_t)idx*4]) = vl;
    } else if (idx < NX4 + 4*NW4) {
        int t = idx - NX4;
        const int w = t / NW4; t -= w*NW4;
        const float* W = (w==0) ? Wq : (w==1) ? Wk : (w==2) ? Wv : Wo;
        const int k  = t / 96;              // source row (k index)
        const int n4 = (t - k*96) * 4;      // source col base (n index)
        const float4 v = ld4(&W[(size_t)k*DM + n4]);
        u16* oh = Wth + (size_t)w*DM*DM;
        u16* ol = Wtl + (size_t)w*DM*DM;
        u16 h,l;
        bf_split(v.x,h,l); oh[(size_t)(n4+0)*DM + k] = h; ol[(size_t)(n4+0)*DM + k] = l;
        bf_split(v.y,h,l); oh[(size_t)(n4+1)*DM + k] = h; ol[(size_t)(n4+1)*DM + k] = l;
        bf_split(v.z,h,l); oh[(size_t)(n4+2)*DM + k] = h; ol[(size_t)(n4+2)*DM + k] = l;
        bf_split(v.w,h,l); oh[(size_t)(n4+3)*DM + k] = h; ol[(size_t)(n4+3)*DM + k] = l;
    }
}

// ---------------------------------------------------------------------------
// Kernel 1 (MFMA): Qa/Ka/Va = x @ {Wq,Wk,Wv} + bias via bf16 hi/lo 3-MFMA.
// 128x128 tile, BK=64, 4 waves each computing 64x64 (4x4 frags of 16x16x32).
// ---------------------------------------------------------------------------
__global__ __launch_bounds__(256, 2)
void k_qkvm(const u16* __restrict__ xh, const u16* __restrict__ xl,
            const u16* __restrict__ Wth, const u16* __restrict__ Wtl,
            const float* __restrict__ bq, const float* __restrict__ bk,
            const float* __restrict__ bv,
            float* __restrict__ Qa, float* __restrict__ Ka, float* __restrict__ Va)
{
    __shared__ u16 Ash[2][8192];   // [hi/lo][kgrp*1024 + row*8 + j]
    __shared__ u16 Bsh[2][8192];

    const int tid = threadIdx.x;
    const int r0 = blockIdx.x * 128;
    const int wsel = blockIdx.y / 3;
    const int c0 = (blockIdx.y % 3) * 128;
    const u16* Wh = Wth + (size_t)wsel * DM * DM;
    const u16* Wl = Wtl + (size_t)wsel * DM * DM;

    const int lane = tid & 63, wid = tid >> 6;
    const int wm = wid >> 1, wn = wid & 1;
    const int fr = lane & 15, fg = lane >> 4;

    f32x4 acc[4][4];
    #pragma unroll
    for (int i = 0; i < 4; i++)
        #pragma unroll
        for (int j = 0; j < 4; j++) acc[i][j] = (f32x4){0.f,0.f,0.f,0.f};

    const int srow = tid >> 3;
    const int skc  = tid & 7;

    for (int k0 = 0; k0 < DM; k0 += 64) {
        __syncthreads();
        #pragma unroll
        for (int p = 0; p < 4; ++p) {
            const int row = srow + p*32;
            const int lo = skc*1024 + row*8;
            const int gr = r0 + row;
            uint4 vh = make_uint4(0u,0u,0u,0u), vl = vh;
            if (gr < MROWS) {
                const size_t ga = (size_t)gr*DM + k0 + skc*8;
                vh = *reinterpret_cast<const uint4*>(&xh[ga]);
                vl = *reinterpret_cast<const uint4*>(&xl[ga]);
            }
            *reinterpret_cast<uint4*>(&Ash[0][lo]) = vh;
            *reinterpret_cast<uint4*>(&Ash[1][lo]) = vl;
            const size_t gb = (size_t)(c0 + row)*DM + k0 + skc*8;
            *reinterpret_cast<uint4*>(&Bsh[0][lo]) = *reinterpret_cast<const uint4*>(&Wh[gb]);
            *reinterpret_cast<uint4*>(&Bsh[1][lo]) = *reinterpret_cast<const uint4*>(&Wl[gb]);
        }
        __syncthreads();
        #pragma unroll
        for (int ks = 0; ks < 2; ++ks) {
            const int kb = (ks*4 + fg) * 1024;
            bf16x8 ah[4], al[4], bh[4], blo[4];
            #pragma unroll
            for (int t = 0; t < 4; ++t) {
                const int ro = kb + (wm*64 + t*16 + fr)*8;
                ah[t] = *reinterpret_cast<const bf16x8*>(&Ash[0][ro]);
                al[t] = *reinterpret_cast<const bf16x8*>(&Ash[1][ro]);
                const int co = kb + (wn*64 + t*16 + fr)*8;
                bh[t]  = *reinterpret_cast<const bf16x8*>(&Bsh[0][co]);
                blo[t] = *reinterpret_cast<const bf16x8*>(&Bsh[1][co]);
            }
            #pragma unroll
            for (int mt = 0; mt < 4; ++mt)
                #pragma unroll
                for (int nt = 0; nt < 4; ++nt) {
                    acc[mt][nt] = __builtin_amdgcn_mfma_f32_16x16x32_bf16(ah[mt], bh[nt],  acc[mt][nt], 0,0,0);
                    acc[mt][nt] = __builtin_amdgcn_mfma_f32_16x16x32_bf16(al[mt], bh[nt],  acc[mt][nt], 0,0,0);
                    acc[mt][nt] = __builtin_amdgcn_mfma_f32_16x16x32_bf16(ah[mt], blo[nt], acc[mt][nt], 0,0,0);
                }
        }
    }

    const float* bias = (wsel==0) ? bq : (wsel==1) ? bk : bv;
    float*       outp = (wsel==0) ? Qa : (wsel==1) ? Ka : Va;
    #pragma unroll
    for (int mt = 0; mt < 4; ++mt) {
        const int rbase = r0 + wm*64 + mt*16 + fg*4;
        #pragma unroll
        for (int nt = 0; nt < 4; ++nt) {
            const int col = c0 + wn*64 + nt*16 + fr;
            const float bb_ = bias[col];
            #pragma unroll
            for (int i = 0; i < 4; ++i) {
                const int rr = rbase + i;
                if (rr < MROWS) outp[(size_t)rr*DM + col] = acc[mt][nt][i] + bb_;
            }
        }
    }
}

// ---------------------------------------------------------------------------
// Kernel 2: attention per token, all 8 heads at once. ctx written as bf16
// hi/lo (ch/cl) to feed the MFMA Wo-GEMM directly.
// ---------------------------------------------------------------------------
__global__ __launch_bounds__(256, 3)
void k_attn(const float* __restrict__ Qa,
            const float* __restrict__ Ka,
            const float* __restrict__ Va,
            const int* __restrict__ topk,
            u16* __restrict__ ch, u16* __restrict__ cl)
{
    __shared__ float Qs[6*384];
    __shared__ float Sm[48*98];
    __shared__ float Rs[16*388];
    __shared__ int   idxs[NK];

    const int tid = threadIdx.x;
    const int bn  = blockIdx.x;
    const int bb  = (bn >= NN) ? NN : 0;
    const size_t qbase = (size_t)bn * (ND*DM);

    if (tid < NK) idxs[tid] = topk[bn*NK + tid];
    {
        const float4* src = (const float4*)(Qa + qbase);
        float4* dst = (float4*)Qs;
        #pragma unroll
        for (int p = 0; p < 3; p++) {
            const int i = tid + p*256;
            if (i < 576) dst[i] = src[i];
        }
    }
    __syncthreads();

    const int s_l = tid & 15;
    const int hh8 = (tid >> 4) & 7;
    const int lh  = tid >> 7;

    for (int c = 0; c < 6; ++c) {
        #pragma unroll
        for (int p = 0; p < 6; p++) {
            const int p4 = tid + p*256;
            const int r16 = p4 / 96, c4 = p4 - r16*96;
            const int sg = c*16 + r16;
            const int k = sg / 6, d = sg - k*6;
            const float4 v = ld4(&Ka[((size_t)(bb + idxs[k])*ND + d)*DM + c4*4]);
            st4(&Rs[r16*388 + c4*4], v);
        }
        __syncthreads();
        {
            const float* Krow = &Rs[s_l*388 + hh8*48];
            const float* Q0 = &Qs[(lh*3+0)*384 + hh8*48];
            const float* Q1 = &Qs[(lh*3+1)*384 + hh8*48];
            const float* Q2 = &Qs[(lh*3+2)*384 + hh8*48];
            float a0 = 0.f, a1 = 0.f, a2 = 0.f;
            #pragma unroll
            for (int j = 0; j < 12; ++j) {
                const float4 kv = ld4(&Krow[4*j]);
                const float4 q0 = ld4(&Q0[4*j]);
                const float4 q1 = ld4(&Q1[4*j]);
                const float4 q2 = ld4(&Q2[4*j]);
                a0 = fmaf(kv.x,q0.x, fmaf(kv.y,q0.y, fmaf(kv.z,q0.z, fmaf(kv.w,q0.w, a0))));
                a1 = fmaf(kv.x,q1.x, fmaf(kv.y,q1.y, fmaf(kv.z,q1.z, fmaf(kv.w,q1.w, a1))));
                a2 = fmaf(kv.x,q2.x, fmaf(kv.y,q2.y, fmaf(kv.z,q2.z, fmaf(kv.w,q2.w, a2))));
            }
            const int sg = c*16 + s_l;
            Sm[(hh8*6 + lh*3 + 0)*98 + sg] = a0 * SCALE;
            Sm[(hh8*6 + lh*3 + 1)*98 + sg] = a1 * SCALE;
            Sm[(hh8*6 + lh*3 + 2)*98 + sg] = a2 * SCALE;
        }
        __syncthreads();
    }

    {
        const int g = tid >> 2, l4 = tid & 3;
        if (g < 48) {
            float* row = &Sm[g*98];
            float m = -3.0e38f;
            #pragma unroll
            for (int i = 0; i < 24; ++i) m = fmaxf(m, row[l4 + 4*i]);
            m = fmaxf(m, __shfl_xor(m, 1));
            m = fmaxf(m, __shfl_xor(m, 2));
            float e[24];
            float sum = 0.f;
            #pragma unroll
            for (int i = 0; i < 24; ++i) { e[i] = __expf(row[l4 + 4*i] - m); sum += e[i]; }
            sum += __shfl_xor(sum, 1);
            sum += __shfl_xor(sum, 2);
            const float inv = 1.f / sum;
            #pragma unroll
            for (int i = 0; i < 24; ++i) row[l4 + 4*i] = e[i] * inv;
        }
    }
    __syncthreads();

    const int g  = tid >> 2;
    const int jl = tid & 3;
    const int hh = g / 6, ll = g - hh*6;
    float4 acc0 = make_float4(0.f,0.f,0.f,0.f);
    float4 acc1 = make_float4(0.f,0.f,0.f,0.f);
    float4 acc2 = make_float4(0.f,0.f,0.f,0.f);

    for (int c = 0; c < 6; ++c) {
        #pragma unroll
        for (int p = 0; p < 6; p++) {
            const int p4 = tid + p*256;
            const int r16 = p4 / 96, c4 = p4 - r16*96;
            const int sg = c*16 + r16;
            const int k = sg / 6, d = sg - k*6;
            const float4 v = ld4(&Va[((size_t)(bb + idxs[k])*ND + d)*DM + c4*4]);
            st4(&Rs[r16*388 + c4*4], v);
        }
        __syncthreads();
        if (g < 48) {
            const float* arow = &Sm[g*98 + c*16];
            #pragma unroll
            for (int s = 0; s < 16; ++s) {
                const float a = arow[s];
                const float* vr = &Rs[s*388 + hh*48 + 4*jl];
                const float4 v0 = ld4(&vr[0]);
                const float4 v1 = ld4(&vr[16]);
                const float4 v2 = ld4(&vr[32]);
                acc0.x = fmaf(a, v0.x, acc0.x); acc0.y = fmaf(a, v0.y, acc0.y);
                acc0.z = fmaf(a, v0.z, acc0.z); acc0.w = fmaf(a, v0.w, acc0.w);
                acc1.x = fmaf(a, v1.x, acc1.x); acc1.y = fmaf(a, v1.y, acc1.y);
                acc1.z = fmaf(a, v1.z, acc1.z); acc1.w = fmaf(a, v1.w, acc1.w);
                acc2.x = fmaf(a, v2.x, acc2.x); acc2.y = fmaf(a, v2.y, acc2.y);
                acc2.z = fmaf(a, v2.z, acc2.z); acc2.w = fmaf(a, v2.w, acc2.w);
            }
        }
        __syncthreads();
    }

    if (g < 48) {
        const size_t base = qbase + (size_t)ll*DM + hh*48 + 4*jl;
        float av[12] = {acc0.x,acc0.y,acc0.z,acc0.w, acc1.x,acc1.y,acc1.z,acc1.w,
                        acc2.x,acc2.y,acc2.z,acc2.w};
        #pragma unroll
        for (int q = 0; q < 3; ++q) {
            ushort4 vh, vl;
            u16 h, l;
            bf_split(av[4*q+0], h, l); vh.x = h; vl.x = l;
            bf_split(av[4*q+1], h, l); vh.y = h; vl.y = l;
            bf_split(av[4*q+2], h, l); vh.z = h; vl.z = l;
            bf_split(av[4*q+3], h, l); vh.w = h; vl.w = l;
            *reinterpret_cast<ushort4*>(&ch[base + 16*q]) = vh;
            *reinterpret_cast<ushort4*>(&cl[base + 16*q]) = vl;
        }
    }
}

// ---------------------------------------------------------------------------
// Kernel 3 (MFMA): fused = LN(x + ctx@Wo + bo) -> out.
// Same GEMM structure as k_qkvm (wsel=3 weight slice). LN done in-register:
// a 32-col LN group = two adjacent 16-wide fragment columns on the same 16
// lanes -> 4-step shfl_xor reductions, no LDS round-trip.
// ---------------------------------------------------------------------------
__global__ __launch_bounds__(256, 2)
void k_out1(const u16* __restrict__ ch, const u16* __restrict__ cl,
            const u16* __restrict__ Wth, const u16* __restrict__ Wtl,
            const float* __restrict__ x, const float* __restrict__ bo,
            const float* __restrict__ ln_g, const float* __restrict__ ln_b,
            float* __restrict__ out)
{
    __shared__ u16 Ash[2][8192];
    __shared__ u16 Bsh[2][8192];

    const int tid = threadIdx.x;
    const int r0 = blockIdx.x * 128;
    const int c0 = blockIdx.y * 128;
    const u16* Wh = Wth + (size_t)3 * DM * DM;
    const u16* Wl = Wtl + (size_t)3 * DM * DM;

    const int lane = tid & 63, wid = tid >> 6;
    const int wm = wid >> 1, wn = wid & 1;
    const int fr = lane & 15, fg = lane >> 4;

    f32x4 acc[4][4];
    #pragma unroll
    for (int i = 0; i < 4; i++)
        #pragma unroll
        for (int j = 0; j < 4; j++) acc[i][j] = (f32x4){0.f,0.f,0.f,0.f};

    const int srow = tid >> 3;
    const int skc  = tid & 7;

    for (int k0 = 0; k0 < DM; k0 += 64) {
        __syncthreads();
        #pragma unroll
        for (int p = 0; p < 4; ++p) {
            const int row = srow + p*32;
            const int lo = skc*1024 + row*8;
            const int gr = r0 + row;
            uint4 vh = make_uint4(0u,0u,0u,0u), vl = vh;
            if (gr < MROWS) {
                const size_t ga = (size_t)gr*DM + k0 + skc*8;
                vh = *reinterpret_cast<const uint4*>(&ch[ga]);
                vl = *reinterpret_cast<const uint4*>(&cl[ga]);
            }
            *reinterpret_cast<uint4*>(&Ash[0][lo]) = vh;
            *reinterpret_cast<uint4*>(&Ash[1][lo]) = vl;
            const size_t gb = (size_t)(c0 + row)*DM + k0 + skc*8;
            *reinterpret_cast<uint4*>(&Bsh[0][lo]) = *reinterpret_cast<const uint4*>(&Wh[gb]);
            *reinterpret_cast<uint4*>(&Bsh[1][lo]) = *reinterpret_cast<const uint4*>(&Wl[gb]);
        }
        __syncthreads();
        #pragma unroll
        for (int ks = 0; ks < 2; ++ks) {
            const int kb = (ks*4 + fg) * 1024;
            bf16x8 ah[4], al[4], bh[4], blo[4];
            #pragma unroll
            for (int t = 0; t < 4; ++t) {
                const int ro = kb + (wm*64 + t*16 + fr)*8;
                ah[t] = *reinterpret_cast<const bf16x8*>(&Ash[0][ro]);
                al[t] = *reinterpret_cast<const bf16x8*>(&Ash[1][ro]);
                const int co = kb + (wn*64 + t*16 + fr)*8;
                bh[t]  = *reinterpret_cast<const bf16x8*>(&Bsh[0][co]);
                blo[t] = *reinterpret_cast<const bf16x8*>(&Bsh[1][co]);
            }
            #pragma unroll
            for (int mt = 0; mt < 4; ++mt)
                #pragma unroll
                for (int nt = 0; nt < 4; ++nt) {
                    acc[mt][nt] = __builtin_amdgcn_mfma_f32_16x16x32_bf16(ah[mt], bh[nt],  acc[mt][nt], 0,0,0);
                    acc[mt][nt] = __builtin_amdgcn_mfma_f32_16x16x32_bf16(al[mt], bh[nt],  acc[mt][nt], 0,0,0);
                    acc[mt][nt] = __builtin_amdgcn_mfma_f32_16x16x32_bf16(ah[mt], blo[nt], acc[mt][nt], 0,0,0);
                }
        }
    }

    // -------- epilogue: +bo +x, LayerNorm per 32-col group, store fused ----
    const float lgA = ln_g[fr],      lgB = ln_g[fr+16];
    const float lbA = ln_b[fr],      lbB = ln_b[fr+16];
    float bo_[4];
    #pragma unroll
    for (int nt = 0; nt < 4; ++nt) bo_[nt] = bo[c0 + wn*64 + nt*16 + fr];

    #pragma unroll
    for (int mt = 0; mt < 4; ++mt) {
        const int rbase = r0 + wm*64 + mt*16 + fg*4;
        #pragma unroll
        for (int g2 = 0; g2 < 2; ++g2) {
            const int ca = c0 + wn*64 + g2*32 + fr;
            const int cb = ca + 16;
            #pragma unroll
            for (int i = 0; i < 4; ++i) {
                const int rr = rbase + i;
                float ha = acc[mt][2*g2][i]   + bo_[2*g2];
                float hb = acc[mt][2*g2+1][i] + bo_[2*g2+1];
                if (rr < MROWS) {
                    ha += x[(size_t)rr*DM + ca];
                    hb += x[(size_t)rr*DM + cb];
                }
                float s = ha + hb;
                s += __shfl_xor(s, 1); s += __shfl_xor(s, 2);
                s += __shfl_xor(s, 4); s += __shfl_xor(s, 8);
                const float mu = s * 0.03125f;
                const float da = ha - mu, db = hb - mu;
                float v = da*da + db*db;
                v += __shfl_xor(v, 1); v += __shfl_xor(v, 2);
                v += __shfl_xor(v, 4); v += __shfl_xor(v, 8);
                const float rstd = 1.0f / sqrtf(v * 0.03125f + 1e-5f);
                if (rr < MROWS) {
                    out[(size_t)rr*DM + ca] = da * rstd * lgA + lbA;
                    out[(size_t)rr*DM + cb] = db * rstd * lgB + lbB;
                }
            }
        }
    }
}

// ---------------------------------------------------------------------------
// Kernel 4: out += gelu(out@W1 + b1)@W2 + b2, per (row, 32-col group).
// ---------------------------------------------------------------------------
__global__ __launch_bounds__(256, 2)
void k_mlp(float* __restrict__ out,
           const float* __restrict__ W1, const float* __restrict__ b1,
           const float* __restrict__ W2, const float* __restrict__ b2)
{
    __shared__ float W1s[2048];    // [c][o] (32x64)
    __shared__ float W2t[2048];    // transposed: [c][o] (32x64)
    __shared__ float b1s[64];
    __shared__ float b2s[32];

    const int tid = threadIdx.x;
    for (int p = tid; p < 2048; p += 256) {
        W1s[p] = W1[p];
        const int o = p >> 5, c = p & 31;   // W2 is [64][32]
        W2t[c*64 + o] = W2[p];
    }
    if (tid < 64) b1s[tid] = b1[tid];
    if (tid < 32) b2s[tid] = b2[tid];
    __syncthreads();

    const int idx = blockIdx.x*256 + tid;
    if (idx >= MROWS*12) return;
    const int row = idx / 12, g = idx - row*12;
    float* p = &out[(size_t)row*DM + g*32];

    float f[32];
    #pragma unroll
    for (int j = 0; j < 8; ++j) {
        const float4 v = ld4(&p[4*j]);
        f[4*j+0]=v.x; f[4*j+1]=v.y; f[4*j+2]=v.z; f[4*j+3]=v.w;
    }

    float y[64];
    #pragma unroll
    for (int o4 = 0; o4 < 16; ++o4) {
        const float4 bv = ld4(&b1s[4*o4]);
        y[4*o4+0]=bv.x; y[4*o4+1]=bv.y; y[4*o4+2]=bv.z; y[4*o4+3]=bv.w;
    }
    #pragma unroll
    for (int c = 0; c < 32; ++c) {
        const float fc = f[c];
        const float4* w = (const float4*)&W1s[c*64];
        #pragma unroll
        for (int j = 0; j < 16; ++j) {
            const float4 wv = w[j];
            y[4*j+0] = fmaf(fc, wv.x, y[4*j+0]);
            y[4*j+1] = fmaf(fc, wv.y, y[4*j+1]);
            y[4*j+2] = fmaf(fc, wv.z, y[4*j+2]);
            y[4*j+3] = fmaf(fc, wv.w, y[4*j+3]);
        }
    }
    #pragma unroll
    for (int o = 0; o < 64; ++o) {
        const float v = y[o];
        y[o] = 0.5f * v * (1.0f + erff(v * GELU_K));
    }
    #pragma unroll
    for (int c = 0; c < 32; ++c) {
        float zc = b2s[c];
        const float4* w = (const float4*)&W2t[c*64];
        #pragma unroll
        for (int j = 0; j < 16; ++j) {
            const float4 wv = w[j];
            zc = fmaf(y[4*j+0], wv.x, zc);
            zc = fmaf(y[4*j+1], wv.y, zc);
            zc = fmaf(y[4*j+2], wv.z, zc);
            zc = fmaf(y[4*j+3], wv.w, zc);
        }
        p[c] = f[c] + zc;
    }
}

// ---------------------------------------------------------------------------
extern "C" void kernel_launch(void* const* d_in, const int* in_sizes, int n_in,
                              void* d_out, int out_size, void* d_ws, size_t ws_size,
                              hipStream_t stream)
{
    const float* x   = (const float*)d_in[0];
    const int*   tk  = (const int*)  d_in[1];
    const float* Wq  = (const float*)d_in[2];
    const float* bq  = (const float*)d_in[3];
    const float* Wk  = (const float*)d_in[4];
    const float* bk  = (const float*)d_in[5];
    const float* Wv  = (const float*)d_in[6];
    const float* bv  = (const float*)d_in[7];
    const float* Wo  = (const float*)d_in[8];
    const float* bo  = (const float*)d_in[9];
    const float* lng = (const float*)d_in[10];
    const float* lnb = (const float*)d_in[11];
    const float* W1  = (const float*)d_in[12];
    const float* b1  = (const float*)d_in[13];
    const float* W2  = (const float*)d_in[14];
    const float* b2  = (const float*)d_in[15];
    float* out = (float*)d_out;

    // workspace layout (~76.3 MB):
    //   Qa/Ka/Va fp32 (55.3 MB) | xh/xl bf16 (18.4 MB, reused as ch/cl) |
    //   Wth/Wtl bf16 4 weights (2.4 MB)
    float* Qa = (float*)d_ws;
    float* Ka = Qa + (size_t)MROWS * DM;
    float* Va = Ka + (size_t)MROWS * DM;
    u16* xh  = (u16*)(Va + (size_t)MROWS * DM);
    u16* xl  = xh + (size_t)MROWS * DM;
    u16* Wth = xl + (size_t)MROWS * DM;
    u16* Wtl = Wth + (size_t)4 * DM * DM;
    u16* ch  = xh;   // reuse: xh/xl dead after k_qkvm
    u16* cl  = xl;

    k_convert<<<dim3(5076), 256, 0, stream>>>(x, Wq, Wk, Wv, Wo, xh, xl, Wth, Wtl);
    k_qkvm<<<dim3(94, 9), 256, 0, stream>>>(xh, xl, Wth, Wtl, bq, bk, bv, Qa, Ka, Va);
    k_attn<<<dim3(NTOK), 256, 0, stream>>>(Qa, Ka, Va, tk, ch, cl);
    k_out1<<<dim3(94, 3), 256, 0, stream>>>(ch, cl, Wth, Wtl, x, bo, lng, lnb, out);
    k_mlp<<<dim3(563), 256, 0, stream>>>(out, W1, b1, W2, b2);
}

// Round 7
// 499.319 us; speedup vs baseline: 3.4618x; 3.4618x over previous
//
#include <hip/hip_runtime.h>

// Problem constants (B=2, N=1000, D=6, L=12, C=32, K=16, H=8)
#define NB 2
#define NN 1000
#define ND 6
#define NK 16
#define NH 8
#define DM 384        // L*C
#define MROWS 12000   // B*N*D
#define NTOK 2000     // B*N
#define NS 96         // K*D

typedef unsigned short u16;
typedef __attribute__((ext_vector_type(8))) short bf16x8;   // 8 bf16 (4 VGPRs)
typedef __attribute__((ext_vector_type(4))) float f32x4;

static __device__ __forceinline__ float4 ld4(const float* p){ return *reinterpret_cast<const float4*>(p); }
static __device__ __forceinline__ void st4(float* p, float4 v){ *reinterpret_cast<float4*>(p) = v; }

#define SCALE 0.14433756729740646f   // 1/sqrt(48)
#define GELU_K 0.70710678118654752f  // 1/sqrt(2)

// bf16 round-to-nearest-even of fp32, as raw u16
static __device__ __forceinline__ u16 bf_hi(float a){
    unsigned u = __float_as_uint(a);
    unsigned r = u + 0x7fffu + ((u >> 16) & 1u);
    return (u16)(r >> 16);
}
static __device__ __forceinline__ void bf_split(float a, u16& h, u16& l){
    h = bf_hi(a);
    const float hf = __uint_as_float(((unsigned)h) << 16);
    l = bf_hi(a - hf);
}

// ---------------------------------------------------------------------------
// Kernel 0: convert x -> xh/xl (row-major bf16 hi/lo) and Wq/Wk/Wv/Wo ->
// transposed [n][k] bf16 hi/lo.
// ---------------------------------------------------------------------------
#define NX4 1152000   // x float4 chunks  (12000*384/4)
#define NW4 36864     // per-weight float4 chunks (384*384/4)
__global__ __launch_bounds__(256)
void k_convert(const float* __restrict__ x,
               const float* __restrict__ Wq, const float* __restrict__ Wk,
               const float* __restrict__ Wv, const float* __restrict__ Wo,
               u16* __restrict__ xh, u16* __restrict__ xl,
               u16* __restrict__ Wth, u16* __restrict__ Wtl)
{
    const int idx = blockIdx.x * 256 + threadIdx.x;
    if (idx < NX4) {
        const float4 v = ld4(&x[(size_t)idx*4]);
        u16 h0,l0,h1,l1,h2,l2,h3,l3;
        bf_split(v.x,h0,l0); bf_split(v.y,h1,l1); bf_split(v.z,h2,l2); bf_split(v.w,h3,l3);
        ushort4 vh; vh.x=h0; vh.y=h1; vh.z=h2; vh.w=h3;
        ushort4 vl; vl.x=l0; vl.y=l1; vl.z=l2; vl.w=l3;
        *reinterpret_cast<ushort4*>(&xh[(size_t)idx*4]) = vh;
        *reinterpret_cast<ushort4*>(&xl[(size_t)idx*4]) = vl;
    } else if (idx < NX4 + 4*NW4) {
        int t = idx - NX4;
        const int w = t / NW4; t -= w*NW4;
        const float* W = (w==0) ? Wq : (w==1) ? Wk : (w==2) ? Wv : Wo;
        const int k  = t / 96;              // source row (k index)
        const int n4 = (t - k*96) * 4;      // source col base (n index)
        const float4 v = ld4(&W[(size_t)k*DM + n4]);
        u16* oh = Wth + (size_t)w*DM*DM;
        u16* ol = Wtl + (size_t)w*DM*DM;
        u16 h,l;
        bf_split(v.x,h,l); oh[(size_t)(n4+0)*DM + k] = h; ol[(size_t)(n4+0)*DM + k] = l;
        bf_split(v.y,h,l); oh[(size_t)(n4+1)*DM + k] = h; ol[(size_t)(n4+1)*DM + k] = l;
        bf_split(v.z,h,l); oh[(size_t)(n4+2)*DM + k] = h; ol[(size_t)(n4+2)*DM + k] = l;
        bf_split(v.w,h,l); oh[(size_t)(n4+3)*DM + k] = h; ol[(size_t)(n4+3)*DM + k] = l;
    }
}

// ---------------------------------------------------------------------------
// Kernel 1 (MFMA): Qa/Ka/Va = x @ {Wq,Wk,Wv} + bias via bf16 hi/lo 3-MFMA.
// ---------------------------------------------------------------------------
__global__ __launch_bounds__(256, 2)
void k_qkvm(const u16* __restrict__ xh, const u16* __restrict__ xl,
            const u16* __restrict__ Wth, const u16* __restrict__ Wtl,
            const float* __restrict__ bq, const float* __restrict__ bk,
            const float* __restrict__ bv,
            float* __restrict__ Qa, float* __restrict__ Ka, float* __restrict__ Va)
{
    __shared__ u16 Ash[2][8192];   // [hi/lo][kgrp*1024 + row*8 + j]
    __shared__ u16 Bsh[2][8192];

    const int tid = threadIdx.x;
    const int r0 = blockIdx.x * 128;
    const int wsel = blockIdx.y / 3;
    const int c0 = (blockIdx.y % 3) * 128;
    const u16* Wh = Wth + (size_t)wsel * DM * DM;
    const u16* Wl = Wtl + (size_t)wsel * DM * DM;

    const int lane = tid & 63, wid = tid >> 6;
    const int wm = wid >> 1, wn = wid & 1;
    const int fr = lane & 15, fg = lane >> 4;

    f32x4 acc[4][4];
    #pragma unroll
    for (int i = 0; i < 4; i++)
        #pragma unroll
        for (int j = 0; j < 4; j++) acc[i][j] = (f32x4){0.f,0.f,0.f,0.f};

    const int srow = tid >> 3;
    const int skc  = tid & 7;

    for (int k0 = 0; k0 < DM; k0 += 64) {
        __syncthreads();
        #pragma unroll
        for (int p = 0; p < 4; ++p) {
            const int row = srow + p*32;
            const int lo = skc*1024 + row*8;
            const int gr = r0 + row;
            uint4 vh = make_uint4(0u,0u,0u,0u), vl = vh;
            if (gr < MROWS) {
                const size_t ga = (size_t)gr*DM + k0 + skc*8;
                vh = *reinterpret_cast<const uint4*>(&xh[ga]);
                vl = *reinterpret_cast<const uint4*>(&xl[ga]);
            }
            *reinterpret_cast<uint4*>(&Ash[0][lo]) = vh;
            *reinterpret_cast<uint4*>(&Ash[1][lo]) = vl;
            const size_t gb = (size_t)(c0 + row)*DM + k0 + skc*8;
            *reinterpret_cast<uint4*>(&Bsh[0][lo]) = *reinterpret_cast<const uint4*>(&Wh[gb]);
            *reinterpret_cast<uint4*>(&Bsh[1][lo]) = *reinterpret_cast<const uint4*>(&Wl[gb]);
        }
        __syncthreads();
        #pragma unroll
        for (int ks = 0; ks < 2; ++ks) {
            const int kb = (ks*4 + fg) * 1024;
            bf16x8 ah[4], al[4], bh[4], blo[4];
            #pragma unroll
            for (int t = 0; t < 4; ++t) {
                const int ro = kb + (wm*64 + t*16 + fr)*8;
                ah[t] = *reinterpret_cast<const bf16x8*>(&Ash[0][ro]);
                al[t] = *reinterpret_cast<const bf16x8*>(&Ash[1][ro]);
                const int co = kb + (wn*64 + t*16 + fr)*8;
                bh[t]  = *reinterpret_cast<const bf16x8*>(&Bsh[0][co]);
                blo[t] = *reinterpret_cast<const bf16x8*>(&Bsh[1][co]);
            }
            #pragma unroll
            for (int mt = 0; mt < 4; ++mt)
                #pragma unroll
                for (int nt = 0; nt < 4; ++nt) {
                    acc[mt][nt] = __builtin_amdgcn_mfma_f32_16x16x32_bf16(ah[mt], bh[nt],  acc[mt][nt], 0,0,0);
                    acc[mt][nt] = __builtin_amdgcn_mfma_f32_16x16x32_bf16(al[mt], bh[nt],  acc[mt][nt], 0,0,0);
                    acc[mt][nt] = __builtin_amdgcn_mfma_f32_16x16x32_bf16(ah[mt], blo[nt], acc[mt][nt], 0,0,0);
                }
        }
    }

    const float* bias = (wsel==0) ? bq : (wsel==1) ? bk : bv;
    float*       outp = (wsel==0) ? Qa : (wsel==1) ? Ka : Va;
    #pragma unroll
    for (int mt = 0; mt < 4; ++mt) {
        const int rbase = r0 + wm*64 + mt*16 + fg*4;
        #pragma unroll
        for (int nt = 0; nt < 4; ++nt) {
            const int col = c0 + wn*64 + nt*16 + fr;
            const float bb_ = bias[col];
            #pragma unroll
            for (int i = 0; i < 4; ++i) {
                const int rr = rbase + i;
                if (rr < MROWS) outp[(size_t)rr*DM + col] = acc[mt][nt][i] + bb_;
            }
        }
    }
}

// ---------------------------------------------------------------------------
// Kernel 2: attention per token, all 8 heads at once. ctx written as bf16
// hi/lo (ch/cl) to feed the MFMA Wo-GEMM directly.
// ---------------------------------------------------------------------------
__global__ __launch_bounds__(256, 3)
void k_attn(const float* __restrict__ Qa,
            const float* __restrict__ Ka,
            const float* __restrict__ Va,
            const int* __restrict__ topk,
            u16* __restrict__ ch, u16* __restrict__ cl)
{
    __shared__ float Qs[6*384];
    __shared__ float Sm[48*98];
    __shared__ float Rs[16*388];
    __shared__ int   idxs[NK];

    const int tid = threadIdx.x;
    const int bn  = blockIdx.x;
    const int bb  = (bn >= NN) ? NN : 0;
    const size_t qbase = (size_t)bn * (ND*DM);

    if (tid < NK) idxs[tid] = topk[bn*NK + tid];
    {
        const float4* src = (const float4*)(Qa + qbase);
        float4* dst = (float4*)Qs;
        #pragma unroll
        for (int p = 0; p < 3; p++) {
            const int i = tid + p*256;
            if (i < 576) dst[i] = src[i];
        }
    }
    __syncthreads();

    const int s_l = tid & 15;
    const int hh8 = (tid >> 4) & 7;
    const int lh  = tid >> 7;

    for (int c = 0; c < 6; ++c) {
        #pragma unroll
        for (int p = 0; p < 6; p++) {
            const int p4 = tid + p*256;
            const int r16 = p4 / 96, c4 = p4 - r16*96;
            const int sg = c*16 + r16;
            const int k = sg / 6, d = sg - k*6;
            const float4 v = ld4(&Ka[((size_t)(bb + idxs[k])*ND + d)*DM + c4*4]);
            st4(&Rs[r16*388 + c4*4], v);
        }
        __syncthreads();
        {
            const float* Krow = &Rs[s_l*388 + hh8*48];
            const float* Q0 = &Qs[(lh*3+0)*384 + hh8*48];
            const float* Q1 = &Qs[(lh*3+1)*384 + hh8*48];
            const float* Q2 = &Qs[(lh*3+2)*384 + hh8*48];
            float a0 = 0.f, a1 = 0.f, a2 = 0.f;
            #pragma unroll
            for (int j = 0; j < 12; ++j) {
                const float4 kv = ld4(&Krow[4*j]);
                const float4 q0 = ld4(&Q0[4*j]);
                const float4 q1 = ld4(&Q1[4*j]);
                const float4 q2 = ld4(&Q2[4*j]);
                a0 = fmaf(kv.x,q0.x, fmaf(kv.y,q0.y, fmaf(kv.z,q0.z, fmaf(kv.w,q0.w, a0))));
                a1 = fmaf(kv.x,q1.x, fmaf(kv.y,q1.y, fmaf(kv.z,q1.z, fmaf(kv.w,q1.w, a1))));
                a2 = fmaf(kv.x,q2.x, fmaf(kv.y,q2.y, fmaf(kv.z,q2.z, fmaf(kv.w,q2.w, a2))));
            }
            const int sg = c*16 + s_l;
            Sm[(hh8*6 + lh*3 + 0)*98 + sg] = a0 * SCALE;
            Sm[(hh8*6 + lh*3 + 1)*98 + sg] = a1 * SCALE;
            Sm[(hh8*6 + lh*3 + 2)*98 + sg] = a2 * SCALE;
        }
        __syncthreads();
    }

    {
        const int g = tid >> 2, l4 = tid & 3;
        if (g < 48) {
            float* row = &Sm[g*98];
            float m = -3.0e38f;
            #pragma unroll
            for (int i = 0; i < 24; ++i) m = fmaxf(m, row[l4 + 4*i]);
            m = fmaxf(m, __shfl_xor(m, 1));
            m = fmaxf(m, __shfl_xor(m, 2));
            float e[24];
            float sum = 0.f;
            #pragma unroll
            for (int i = 0; i < 24; ++i) { e[i] = __expf(row[l4 + 4*i] - m); sum += e[i]; }
            sum += __shfl_xor(sum, 1);
            sum += __shfl_xor(sum, 2);
            const float inv = 1.f / sum;
            #pragma unroll
            for (int i = 0; i < 24; ++i) row[l4 + 4*i] = e[i] * inv;
        }
    }
    __syncthreads();

    const int g  = tid >> 2;
    const int jl = tid & 3;
    const int hh = g / 6, ll = g - hh*6;
    float4 acc0 = make_float4(0.f,0.f,0.f,0.f);
    float4 acc1 = make_float4(0.f,0.f,0.f,0.f);
    float4 acc2 = make_float4(0.f,0.f,0.f,0.f);

    for (int c = 0; c < 6; ++c) {
        #pragma unroll
        for (int p = 0; p < 6; p++) {
            const int p4 = tid + p*256;
            const int r16 = p4 / 96, c4 = p4 - r16*96;
            const int sg = c*16 + r16;
            const int k = sg / 6, d = sg - k*6;
            const float4 v = ld4(&Va[((size_t)(bb + idxs[k])*ND + d)*DM + c4*4]);
            st4(&Rs[r16*388 + c4*4], v);
        }
        __syncthreads();
        if (g < 48) {
            const float* arow = &Sm[g*98 + c*16];
            #pragma unroll
            for (int s = 0; s < 16; ++s) {
                const float a = arow[s];
                const float* vr = &Rs[s*388 + hh*48 + 4*jl];
                const float4 v0 = ld4(&vr[0]);
                const float4 v1 = ld4(&vr[16]);
                const float4 v2 = ld4(&vr[32]);
                acc0.x = fmaf(a, v0.x, acc0.x); acc0.y = fmaf(a, v0.y, acc0.y);
                acc0.z = fmaf(a, v0.z, acc0.z); acc0.w = fmaf(a, v0.w, acc0.w);
                acc1.x = fmaf(a, v1.x, acc1.x); acc1.y = fmaf(a, v1.y, acc1.y);
                acc1.z = fmaf(a, v1.z, acc1.z); acc1.w = fmaf(a, v1.w, acc1.w);
                acc2.x = fmaf(a, v2.x, acc2.x); acc2.y = fmaf(a, v2.y, acc2.y);
                acc2.z = fmaf(a, v2.z, acc2.z); acc2.w = fmaf(a, v2.w, acc2.w);
            }
        }
        __syncthreads();
    }

    if (g < 48) {
        const size_t base = qbase + (size_t)ll*DM + hh*48 + 4*jl;
        float av[12] = {acc0.x,acc0.y,acc0.z,acc0.w, acc1.x,acc1.y,acc1.z,acc1.w,
                        acc2.x,acc2.y,acc2.z,acc2.w};
        #pragma unroll
        for (int q = 0; q < 3; ++q) {
            ushort4 vh, vl;
            u16 h, l;
            bf_split(av[4*q+0], h, l); vh.x = h; vl.x = l;
            bf_split(av[4*q+1], h, l); vh.y = h; vl.y = l;
            bf_split(av[4*q+2], h, l); vh.z = h; vl.z = l;
            bf_split(av[4*q+3], h, l); vh.w = h; vl.w = l;
            *reinterpret_cast<ushort4*>(&ch[base + 16*q]) = vh;
            *reinterpret_cast<ushort4*>(&cl[base + 16*q]) = vl;
        }
    }
}

// ---------------------------------------------------------------------------
// Kernel 3 (MFMA): fused = LN(x + ctx@Wo + bo) -> out.  LN in-register via
// 16-lane shfl_xor reductions.
// ---------------------------------------------------------------------------
__global__ __launch_bounds__(256, 2)
void k_out1(const u16* __restrict__ ch, const u16* __restrict__ cl,
            const u16* __restrict__ Wth, const u16* __restrict__ Wtl,
            const float* __restrict__ x, const float* __restrict__ bo,
            const float* __restrict__ ln_g, const float* __restrict__ ln_b,
            float* __restrict__ out)
{
    __shared__ u16 Ash[2][8192];
    __shared__ u16 Bsh[2][8192];

    const int tid = threadIdx.x;
    const int r0 = blockIdx.x * 128;
    const int c0 = blockIdx.y * 128;
    const u16* Wh = Wth + (size_t)3 * DM * DM;
    const u16* Wl = Wtl + (size_t)3 * DM * DM;

    const int lane = tid & 63, wid = tid >> 6;
    const int wm = wid >> 1, wn = wid & 1;
    const int fr = lane & 15, fg = lane >> 4;

    f32x4 acc[4][4];
    #pragma unroll
    for (int i = 0; i < 4; i++)
        #pragma unroll
        for (int j = 0; j < 4; j++) acc[i][j] = (f32x4){0.f,0.f,0.f,0.f};

    const int srow = tid >> 3;
    const int skc  = tid & 7;

    for (int k0 = 0; k0 < DM; k0 += 64) {
        __syncthreads();
        #pragma unroll
        for (int p = 0; p < 4; ++p) {
            const int row = srow + p*32;
            const int lo = skc*1024 + row*8;
            const int gr = r0 + row;
            uint4 vh = make_uint4(0u,0u,0u,0u), vl = vh;
            if (gr < MROWS) {
                const size_t ga = (size_t)gr*DM + k0 + skc*8;
                vh = *reinterpret_cast<const uint4*>(&ch[ga]);
                vl = *reinterpret_cast<const uint4*>(&cl[ga]);
            }
            *reinterpret_cast<uint4*>(&Ash[0][lo]) = vh;
            *reinterpret_cast<uint4*>(&Ash[1][lo]) = vl;
            const size_t gb = (size_t)(c0 + row)*DM + k0 + skc*8;
            *reinterpret_cast<uint4*>(&Bsh[0][lo]) = *reinterpret_cast<const uint4*>(&Wh[gb]);
            *reinterpret_cast<uint4*>(&Bsh[1][lo]) = *reinterpret_cast<const uint4*>(&Wl[gb]);
        }
        __syncthreads();
        #pragma unroll
        for (int ks = 0; ks < 2; ++ks) {
            const int kb = (ks*4 + fg) * 1024;
            bf16x8 ah[4], al[4], bh[4], blo[4];
            #pragma unroll
            for (int t = 0; t < 4; ++t) {
                const int ro = kb + (wm*64 + t*16 + fr)*8;
                ah[t] = *reinterpret_cast<const bf16x8*>(&Ash[0][ro]);
                al[t] = *reinterpret_cast<const bf16x8*>(&Ash[1][ro]);
                const int co = kb + (wn*64 + t*16 + fr)*8;
                bh[t]  = *reinterpret_cast<const bf16x8*>(&Bsh[0][co]);
                blo[t] = *reinterpret_cast<const bf16x8*>(&Bsh[1][co]);
            }
            #pragma unroll
            for (int mt = 0; mt < 4; ++mt)
                #pragma unroll
                for (int nt = 0; nt < 4; ++nt) {
                    acc[mt][nt] = __builtin_amdgcn_mfma_f32_16x16x32_bf16(ah[mt], bh[nt],  acc[mt][nt], 0,0,0);
                    acc[mt][nt] = __builtin_amdgcn_mfma_f32_16x16x32_bf16(al[mt], bh[nt],  acc[mt][nt], 0,0,0);
                    acc[mt][nt] = __builtin_amdgcn_mfma_f32_16x16x32_bf16(ah[mt], blo[nt], acc[mt][nt], 0,0,0);
                }
        }
    }

    // -------- epilogue: +bo +x, LayerNorm per 32-col group, store fused ----
    const float lgA = ln_g[fr],      lgB = ln_g[fr+16];
    const float lbA = ln_b[fr],      lbB = ln_b[fr+16];
    float bo_[4];
    #pragma unroll
    for (int nt = 0; nt < 4; ++nt) bo_[nt] = bo[c0 + wn*64 + nt*16 + fr];

    #pragma unroll
    for (int mt = 0; mt < 4; ++mt) {
        const int rbase = r0 + wm*64 + mt*16 + fg*4;
        #pragma unroll
        for (int g2 = 0; g2 < 2; ++g2) {
            const int ca = c0 + wn*64 + g2*32 + fr;
            const int cb = ca + 16;
            #pragma unroll
            for (int i = 0; i < 4; ++i) {
                const int rr = rbase + i;
                float ha = acc[mt][2*g2][i]   + bo_[2*g2];
                float hb = acc[mt][2*g2+1][i] + bo_[2*g2+1];
                if (rr < MROWS) {
                    ha += x[(size_t)rr*DM + ca];
                    hb += x[(size_t)rr*DM + cb];
                }
                float s = ha + hb;
                s += __shfl_xor(s, 1); s += __shfl_xor(s, 2);
                s += __shfl_xor(s, 4); s += __shfl_xor(s, 8);
                const float mu = s * 0.03125f;
                const float da = ha - mu, db = hb - mu;
                float v = da*da + db*db;
                v += __shfl_xor(v, 1); v += __shfl_xor(v, 2);
                v += __shfl_xor(v, 4); v += __shfl_xor(v, 8);
                const float rstd = 1.0f / sqrtf(v * 0.03125f + 1e-5f);
                if (rr < MROWS) {
                    out[(size_t)rr*DM + ca] = da * rstd * lgA + lbA;
                    out[(size_t)rr*DM + cb] = db * rstd * lgB + lbB;
                }
            }
        }
    }
}

// ---------------------------------------------------------------------------
// Kernel 4 (tiled): out += gelu(out@W1 + b1)@W2 + b2.
// Block = 128 row-groups. F[128][33] + Y[128][66] staged in LDS; two
// micro-tiled fp32 GEMM phases. Max live regs/thread ~80 -> NO SPILL
// (R5's version spilled y[64]+f[32] against the 128-VGPR cap: 3.1 GB of
// scratch HBM traffic, 1400 us).
// ---------------------------------------------------------------------------
__global__ __launch_bounds__(256, 2)
void k_mlp(float* __restrict__ out,
           const float* __restrict__ W1, const float* __restrict__ b1,
           const float* __restrict__ W2, const float* __restrict__ b2)
{
    __shared__ float Fs[128*33];    // fused tile, pad 33
    __shared__ float Ys[128*66];    // gelu(y) tile, pad 66
    __shared__ float W1s[2048];     // [k][o] as given (32x64)
    __shared__ float W2s[2048];     // [o][c] as given (64x32)
    __shared__ float b1s[64];
    __shared__ float b2s[32];

    const int tid = threadIdx.x;
    const int gr0 = blockIdx.x * 128;          // 1125 blocks * 128 = 144000 exact

    // ---- stage weights + F tile
    for (int p = tid; p < 2048; p += 256) { W1s[p] = W1[p]; W2s[p] = W2[p]; }
    if (tid < 64) b1s[tid] = b1[tid];
    if (tid < 32) b2s[tid] = b2[tid];
    {
        const float* src = out + (size_t)gr0 * 32;
        #pragma unroll
        for (int p = 0; p < 4; ++p) {
            const int f4 = tid + p*256;        // 0..1023
            const int r = f4 >> 3, kq = f4 & 7;
            const float4 v = ld4(&src[f4*4]);
            Fs[r*33 + kq*4 + 0] = v.x;
            Fs[r*33 + kq*4 + 1] = v.y;
            Fs[r*33 + kq*4 + 2] = v.z;
            Fs[r*33 + kq*4 + 3] = v.w;
        }
    }
    __syncthreads();

    // ---- layer 1: Y = gelu(F @ W1 + b1), micro-tile 8 rows x 4 cols
    {
        const int tr = tid >> 4;               // 0..15 -> rows tr*8
        const int tc = tid & 15;               // 0..15 -> cols tc*4
        const int r0m = tr*8, c0m = tc*4;
        float y[8][4];
        const float4 bv = ld4(&b1s[c0m]);
        #pragma unroll
        for (int i = 0; i < 8; ++i) { y[i][0]=bv.x; y[i][1]=bv.y; y[i][2]=bv.z; y[i][3]=bv.w; }
        #pragma unroll
        for (int kq = 0; kq < 8; ++kq) {
            float4 a[8];
            #pragma unroll
            for (int i = 0; i < 8; ++i) a[i] = ld4(&Fs[(r0m+i)*33 + kq*4]);
            #pragma unroll
            for (int u = 0; u < 4; ++u) {
                const float4 wv = ld4(&W1s[(kq*4+u)*64 + c0m]);
                #pragma unroll
                for (int i = 0; i < 8; ++i) {
                    const float av = (u==0)?a[i].x:(u==1)?a[i].y:(u==2)?a[i].z:a[i].w;
                    y[i][0] = fmaf(av, wv.x, y[i][0]);
                    y[i][1] = fmaf(av, wv.y, y[i][1]);
                    y[i][2] = fmaf(av, wv.z, y[i][2]);
                    y[i][3] = fmaf(av, wv.w, y[i][3]);
                }
            }
        }
        #pragma unroll
        for (int i = 0; i < 8; ++i)
            #pragma unroll
            for (int j = 0; j < 4; ++j) {
                const float v = y[i][j];
                Ys[(r0m+i)*66 + c0m + j] = 0.5f * v * (1.0f + erff(v * GELU_K));
            }
    }
    __syncthreads();

    // ---- layer 2: out = F + (Y @ W2 + b2), micro-tile 4 rows x 4 cols
    {
        const int tr = tid >> 3;               // 0..31 -> rows tr*4
        const int tc = tid & 7;                // 0..7  -> cols tc*4
        const int r0m = tr*4, c0m = tc*4;
        float z[4][4];
        const float4 bv = ld4(&b2s[c0m]);
        #pragma unroll
        for (int i = 0; i < 4; ++i) { z[i][0]=bv.x; z[i][1]=bv.y; z[i][2]=bv.z; z[i][3]=bv.w; }
        #pragma unroll
        for (int oq = 0; oq < 16; ++oq) {
            float4 a[4];
            #pragma unroll
            for (int i = 0; i < 4; ++i) a[i] = ld4(&Ys[(r0m+i)*66 + oq*4]);
            #pragma unroll
            for (int u = 0; u < 4; ++u) {
                const float4 wv = ld4(&W2s[(oq*4+u)*32 + c0m]);
                #pragma unroll
                for (int i = 0; i < 4; ++i) {
                    const float av = (u==0)?a[i].x:(u==1)?a[i].y:(u==2)?a[i].z:a[i].w;
                    z[i][0] = fmaf(av, wv.x, z[i][0]);
                    z[i][1] = fmaf(av, wv.y, z[i][1]);
                    z[i][2] = fmaf(av, wv.z, z[i][2]);
                    z[i][3] = fmaf(av, wv.w, z[i][3]);
                }
            }
        }
        #pragma unroll
        for (int i = 0; i < 4; ++i) {
            const float* frow = &Fs[(r0m+i)*33 + c0m];
            float4 v;
            v.x = frow[0] + z[i][0];
            v.y = frow[1] + z[i][1];
            v.z = frow[2] + z[i][2];
            v.w = frow[3] + z[i][3];
            st4(&out[((size_t)gr0 + r0m + i)*32 + c0m], v);
        }
    }
}

// ---------------------------------------------------------------------------
extern "C" void kernel_launch(void* const* d_in, const int* in_sizes, int n_in,
                              void* d_out, int out_size, void* d_ws, size_t ws_size,
                              hipStream_t stream)
{
    const float* x   = (const float*)d_in[0];
    const int*   tk  = (const int*)  d_in[1];
    const float* Wq  = (const float*)d_in[2];
    const float* bq  = (const float*)d_in[3];
    const float* Wk  = (const float*)d_in[4];
    const float* bk  = (const float*)d_in[5];
    const float* Wv  = (const float*)d_in[6];
    const float* bv  = (const float*)d_in[7];
    const float* Wo  = (const float*)d_in[8];
    const float* bo  = (const float*)d_in[9];
    const float* lng = (const float*)d_in[10];
    const float* lnb = (const float*)d_in[11];
    const float* W1  = (const float*)d_in[12];
    const float* b1  = (const float*)d_in[13];
    const float* W2  = (const float*)d_in[14];
    const float* b2  = (const float*)d_in[15];
    float* out = (float*)d_out;

    // workspace layout (~76.3 MB):
    //   Qa/Ka/Va fp32 (55.3 MB) | xh/xl bf16 (18.4 MB, reused as ch/cl) |
    //   Wth/Wtl bf16 4 weights (2.4 MB)
    float* Qa = (float*)d_ws;
    float* Ka = Qa + (size_t)MROWS * DM;
    float* Va = Ka + (size_t)MROWS * DM;
    u16* xh  = (u16*)(Va + (size_t)MROWS * DM);
    u16* xl  = xh + (size_t)MROWS * DM;
    u16* Wth = xl + (size_t)MROWS * DM;
    u16* Wtl = Wth + (size_t)4 * DM * DM;
    u16* ch  = xh;   // reuse: xh/xl dead after k_qkvm
    u16* cl  = xl;

    k_convert<<<dim3(5076), 256, 0, stream>>>(x, Wq, Wk, Wv, Wo, xh, xl, Wth, Wtl);
    k_qkvm<<<dim3(94, 9), 256, 0, stream>>>(xh, xl, Wth, Wtl, bq, bk, bv, Qa, Ka, Va);
    k_attn<<<dim3(NTOK), 256, 0, stream>>>(Qa, Ka, Va, tk, ch, cl);
    k_out1<<<dim3(94, 3), 256, 0, stream>>>(ch, cl, Wth, Wtl, x, bo, lng, lnb, out);
    k_mlp<<<dim3(1125), 256, 0, stream>>>(out, W1, b1, W2, b2);
}

// Round 8
// 433.282 us; speedup vs baseline: 3.9894x; 1.1524x over previous
//
#include <hip/hip_runtime.h>

// Problem constants (B=2, N=1000, D=6, L=12, C=32, K=16, H=8)
#define NB 2
#define NN 1000
#define ND 6
#define NK 16
#define NH 8
#define DM 384        // L*C
#define MROWS 12000   // B*N*D
#define NTOK 2000     // B*N
#define NS 96         // K*D

typedef unsigned short u16;
typedef __attribute__((ext_vector_type(8))) short bf16x8;   // 8 bf16 (4 VGPRs)
typedef __attribute__((ext_vector_type(4))) float f32x4;

static __device__ __forceinline__ float4 ld4(const float* p){ return *reinterpret_cast<const float4*>(p); }
static __device__ __forceinline__ void st4(float* p, float4 v){ *reinterpret_cast<float4*>(p) = v; }

#define SCALE 0.14433756729740646f   // 1/sqrt(48)
#define GELU_K 0.70710678118654752f  // 1/sqrt(2)

// bf16 round-to-nearest-even of fp32, as raw u16
static __device__ __forceinline__ u16 bf_hi(float a){
    unsigned u = __float_as_uint(a);
    unsigned r = u + 0x7fffu + ((u >> 16) & 1u);
    return (u16)(r >> 16);
}
static __device__ __forceinline__ void bf_split(float a, u16& h, u16& l){
    h = bf_hi(a);
    const float hf = __uint_as_float(((unsigned)h) << 16);
    l = bf_hi(a - hf);
}

// ---------------------------------------------------------------------------
// Kernel 0: convert x -> xh/xl (row-major bf16 hi/lo) and Wq/Wk/Wv/Wo ->
// transposed [n][k] bf16 hi/lo.
// ---------------------------------------------------------------------------
#define NX4 1152000   // x float4 chunks  (12000*384/4)
#define NW4 36864     // per-weight float4 chunks (384*384/4)
__global__ __launch_bounds__(256)
void k_convert(const float* __restrict__ x,
               const float* __restrict__ Wq, const float* __restrict__ Wk,
               const float* __restrict__ Wv, const float* __restrict__ Wo,
               u16* __restrict__ xh, u16* __restrict__ xl,
               u16* __restrict__ Wth, u16* __restrict__ Wtl)
{
    const int idx = blockIdx.x * 256 + threadIdx.x;
    if (idx < NX4) {
        const float4 v = ld4(&x[(size_t)idx*4]);
        u16 h0,l0,h1,l1,h2,l2,h3,l3;
        bf_split(v.x,h0,l0); bf_split(v.y,h1,l1); bf_split(v.z,h2,l2); bf_split(v.w,h3,l3);
        ushort4 vh; vh.x=h0; vh.y=h1; vh.z=h2; vh.w=h3;
        ushort4 vl; vl.x=l0; vl.y=l1; vl.z=l2; vl.w=l3;
        *reinterpret_cast<ushort4*>(&xh[(size_t)idx*4]) = vh;
        *reinterpret_cast<ushort4*>(&xl[(size_t)idx*4]) = vl;
    } else if (idx < NX4 + 4*NW4) {
        int t = idx - NX4;
        const int w = t / NW4; t -= w*NW4;
        const float* W = (w==0) ? Wq : (w==1) ? Wk : (w==2) ? Wv : Wo;
        const int k  = t / 96;              // source row (k index)
        const int n4 = (t - k*96) * 4;      // source col base (n index)
        const float4 v = ld4(&W[(size_t)k*DM + n4]);
        u16* oh = Wth + (size_t)w*DM*DM;
        u16* ol = Wtl + (size_t)w*DM*DM;
        u16 h,l;
        bf_split(v.x,h,l); oh[(size_t)(n4+0)*DM + k] = h; ol[(size_t)(n4+0)*DM + k] = l;
        bf_split(v.y,h,l); oh[(size_t)(n4+1)*DM + k] = h; ol[(size_t)(n4+1)*DM + k] = l;
        bf_split(v.z,h,l); oh[(size_t)(n4+2)*DM + k] = h; ol[(size_t)(n4+2)*DM + k] = l;
        bf_split(v.w,h,l); oh[(size_t)(n4+3)*DM + k] = h; ol[(size_t)(n4+3)*DM + k] = l;
    }
}

// ---------------------------------------------------------------------------
// Kernel 1 (MFMA): Qa/Ka/Va = x @ {Wq,Wk,Wv} + bias via bf16 hi/lo 3-MFMA.
// ---------------------------------------------------------------------------
__global__ __launch_bounds__(256, 2)
void k_qkvm(const u16* __restrict__ xh, const u16* __restrict__ xl,
            const u16* __restrict__ Wth, const u16* __restrict__ Wtl,
            const float* __restrict__ bq, const float* __restrict__ bk,
            const float* __restrict__ bv,
            float* __restrict__ Qa, float* __restrict__ Ka, float* __restrict__ Va)
{
    __shared__ u16 Ash[2][8192];   // [hi/lo][kgrp*1024 + row*8 + j]
    __shared__ u16 Bsh[2][8192];

    const int tid = threadIdx.x;
    const int r0 = blockIdx.x * 128;
    const int wsel = blockIdx.y / 3;
    const int c0 = (blockIdx.y % 3) * 128;
    const u16* Wh = Wth + (size_t)wsel * DM * DM;
    const u16* Wl = Wtl + (size_t)wsel * DM * DM;

    const int lane = tid & 63, wid = tid >> 6;
    const int wm = wid >> 1, wn = wid & 1;
    const int fr = lane & 15, fg = lane >> 4;

    f32x4 acc[4][4];
    #pragma unroll
    for (int i = 0; i < 4; i++)
        #pragma unroll
        for (int j = 0; j < 4; j++) acc[i][j] = (f32x4){0.f,0.f,0.f,0.f};

    const int srow = tid >> 3;
    const int skc  = tid & 7;

    for (int k0 = 0; k0 < DM; k0 += 64) {
        __syncthreads();
        #pragma unroll
        for (int p = 0; p < 4; ++p) {
            const int row = srow + p*32;
            const int lo = skc*1024 + row*8;
            const int gr = r0 + row;
            uint4 vh = make_uint4(0u,0u,0u,0u), vl = vh;
            if (gr < MROWS) {
                const size_t ga = (size_t)gr*DM + k0 + skc*8;
                vh = *reinterpret_cast<const uint4*>(&xh[ga]);
                vl = *reinterpret_cast<const uint4*>(&xl[ga]);
            }
            *reinterpret_cast<uint4*>(&Ash[0][lo]) = vh;
            *reinterpret_cast<uint4*>(&Ash[1][lo]) = vl;
            const size_t gb = (size_t)(c0 + row)*DM + k0 + skc*8;
            *reinterpret_cast<uint4*>(&Bsh[0][lo]) = *reinterpret_cast<const uint4*>(&Wh[gb]);
            *reinterpret_cast<uint4*>(&Bsh[1][lo]) = *reinterpret_cast<const uint4*>(&Wl[gb]);
        }
        __syncthreads();
        #pragma unroll
        for (int ks = 0; ks < 2; ++ks) {
            const int kb = (ks*4 + fg) * 1024;
            bf16x8 ah[4], al[4], bh[4], blo[4];
            #pragma unroll
            for (int t = 0; t < 4; ++t) {
                const int ro = kb + (wm*64 + t*16 + fr)*8;
                ah[t] = *reinterpret_cast<const bf16x8*>(&Ash[0][ro]);
                al[t] = *reinterpret_cast<const bf16x8*>(&Ash[1][ro]);
                const int co = kb + (wn*64 + t*16 + fr)*8;
                bh[t]  = *reinterpret_cast<const bf16x8*>(&Bsh[0][co]);
                blo[t] = *reinterpret_cast<const bf16x8*>(&Bsh[1][co]);
            }
            #pragma unroll
            for (int mt = 0; mt < 4; ++mt)
                #pragma unroll
                for (int nt = 0; nt < 4; ++nt) {
                    acc[mt][nt] = __builtin_amdgcn_mfma_f32_16x16x32_bf16(ah[mt], bh[nt],  acc[mt][nt], 0,0,0);
                    acc[mt][nt] = __builtin_amdgcn_mfma_f32_16x16x32_bf16(al[mt], bh[nt],  acc[mt][nt], 0,0,0);
                    acc[mt][nt] = __builtin_amdgcn_mfma_f32_16x16x32_bf16(ah[mt], blo[nt], acc[mt][nt], 0,0,0);
                }
        }
    }

    const float* bias = (wsel==0) ? bq : (wsel==1) ? bk : bv;
    float*       outp = (wsel==0) ? Qa : (wsel==1) ? Ka : Va;
    #pragma unroll
    for (int mt = 0; mt < 4; ++mt) {
        const int rbase = r0 + wm*64 + mt*16 + fg*4;
        #pragma unroll
        for (int nt = 0; nt < 4; ++nt) {
            const int col = c0 + wn*64 + nt*16 + fr;
            const float bb_ = bias[col];
            #pragma unroll
            for (int i = 0; i < 4; ++i) {
                const int rr = rbase + i;
                if (rr < MROWS) outp[(size_t)rr*DM + col] = acc[mt][nt][i] + bb_;
            }
        }
    }
}

// ---------------------------------------------------------------------------
// Kernel 2: attention per token, all 8 heads at once. ctx written as bf16
// hi/lo (ch/cl) to feed the MFMA Wo-GEMM directly.
// ---------------------------------------------------------------------------
__global__ __launch_bounds__(256, 3)
void k_attn(const float* __restrict__ Qa,
            const float* __restrict__ Ka,
            const float* __restrict__ Va,
            const int* __restrict__ topk,
            u16* __restrict__ ch, u16* __restrict__ cl)
{
    __shared__ float Qs[6*384];
    __shared__ float Sm[48*98];
    __shared__ float Rs[16*388];
    __shared__ int   idxs[NK];

    const int tid = threadIdx.x;
    const int bn  = blockIdx.x;
    const int bb  = (bn >= NN) ? NN : 0;
    const size_t qbase = (size_t)bn * (ND*DM);

    if (tid < NK) idxs[tid] = topk[bn*NK + tid];
    {
        const float4* src = (const float4*)(Qa + qbase);
        float4* dst = (float4*)Qs;
        #pragma unroll
        for (int p = 0; p < 3; p++) {
            const int i = tid + p*256;
            if (i < 576) dst[i] = src[i];
        }
    }
    __syncthreads();

    const int s_l = tid & 15;
    const int hh8 = (tid >> 4) & 7;
    const int lh  = tid >> 7;

    for (int c = 0; c < 6; ++c) {
        #pragma unroll
        for (int p = 0; p < 6; p++) {
            const int p4 = tid + p*256;
            const int r16 = p4 / 96, c4 = p4 - r16*96;
            const int sg = c*16 + r16;
            const int k = sg / 6, d = sg - k*6;
            const float4 v = ld4(&Ka[((size_t)(bb + idxs[k])*ND + d)*DM + c4*4]);
            st4(&Rs[r16*388 + c4*4], v);
        }
        __syncthreads();
        {
            const float* Krow = &Rs[s_l*388 + hh8*48];
            const float* Q0 = &Qs[(lh*3+0)*384 + hh8*48];
            const float* Q1 = &Qs[(lh*3+1)*384 + hh8*48];
            const float* Q2 = &Qs[(lh*3+2)*384 + hh8*48];
            float a0 = 0.f, a1 = 0.f, a2 = 0.f;
            #pragma unroll
            for (int j = 0; j < 12; ++j) {
                const float4 kv = ld4(&Krow[4*j]);
                const float4 q0 = ld4(&Q0[4*j]);
                const float4 q1 = ld4(&Q1[4*j]);
                const float4 q2 = ld4(&Q2[4*j]);
                a0 = fmaf(kv.x,q0.x, fmaf(kv.y,q0.y, fmaf(kv.z,q0.z, fmaf(kv.w,q0.w, a0))));
                a1 = fmaf(kv.x,q1.x, fmaf(kv.y,q1.y, fmaf(kv.z,q1.z, fmaf(kv.w,q1.w, a1))));
                a2 = fmaf(kv.x,q2.x, fmaf(kv.y,q2.y, fmaf(kv.z,q2.z, fmaf(kv.w,q2.w, a2))));
            }
            const int sg = c*16 + s_l;
            Sm[(hh8*6 + lh*3 + 0)*98 + sg] = a0 * SCALE;
            Sm[(hh8*6 + lh*3 + 1)*98 + sg] = a1 * SCALE;
            Sm[(hh8*6 + lh*3 + 2)*98 + sg] = a2 * SCALE;
        }
        __syncthreads();
    }

    {
        const int g = tid >> 2, l4 = tid & 3;
        if (g < 48) {
            float* row = &Sm[g*98];
            float m = -3.0e38f;
            #pragma unroll
            for (int i = 0; i < 24; ++i) m = fmaxf(m, row[l4 + 4*i]);
            m = fmaxf(m, __shfl_xor(m, 1));
            m = fmaxf(m, __shfl_xor(m, 2));
            float e[24];
            float sum = 0.f;
            #pragma unroll
            for (int i = 0; i < 24; ++i) { e[i] = __expf(row[l4 + 4*i] - m); sum += e[i]; }
            sum += __shfl_xor(sum, 1);
            sum += __shfl_xor(sum, 2);
            const float inv = 1.f / sum;
            #pragma unroll
            for (int i = 0; i < 24; ++i) row[l4 + 4*i] = e[i] * inv;
        }
    }
    __syncthreads();

    const int g  = tid >> 2;
    const int jl = tid & 3;
    const int hh = g / 6, ll = g - hh*6;
    float4 acc0 = make_float4(0.f,0.f,0.f,0.f);
    float4 acc1 = make_float4(0.f,0.f,0.f,0.f);
    float4 acc2 = make_float4(0.f,0.f,0.f,0.f);

    for (int c = 0; c < 6; ++c) {
        #pragma unroll
        for (int p = 0; p < 6; p++) {
            const int p4 = tid + p*256;
            const int r16 = p4 / 96, c4 = p4 - r16*96;
            const int sg = c*16 + r16;
            const int k = sg / 6, d = sg - k*6;
            const float4 v = ld4(&Va[((size_t)(bb + idxs[k])*ND + d)*DM + c4*4]);
            st4(&Rs[r16*388 + c4*4], v);
        }
        __syncthreads();
        if (g < 48) {
            const float* arow = &Sm[g*98 + c*16];
            #pragma unroll
            for (int s = 0; s < 16; ++s) {
                const float a = arow[s];
                const float* vr = &Rs[s*388 + hh*48 + 4*jl];
                const float4 v0 = ld4(&vr[0]);
                const float4 v1 = ld4(&vr[16]);
                const float4 v2 = ld4(&vr[32]);
                acc0.x = fmaf(a, v0.x, acc0.x); acc0.y = fmaf(a, v0.y, acc0.y);
                acc0.z = fmaf(a, v0.z, acc0.z); acc0.w = fmaf(a, v0.w, acc0.w);
                acc1.x = fmaf(a, v1.x, acc1.x); acc1.y = fmaf(a, v1.y, acc1.y);
                acc1.z = fmaf(a, v1.z, acc1.z); acc1.w = fmaf(a, v1.w, acc1.w);
                acc2.x = fmaf(a, v2.x, acc2.x); acc2.y = fmaf(a, v2.y, acc2.y);
                acc2.z = fmaf(a, v2.z, acc2.z); acc2.w = fmaf(a, v2.w, acc2.w);
            }
        }
        __syncthreads();
    }

    if (g < 48) {
        const size_t base = qbase + (size_t)ll*DM + hh*48 + 4*jl;
        float av[12] = {acc0.x,acc0.y,acc0.z,acc0.w, acc1.x,acc1.y,acc1.z,acc1.w,
                        acc2.x,acc2.y,acc2.z,acc2.w};
        #pragma unroll
        for (int q = 0; q < 3; ++q) {
            ushort4 vh, vl;
            u16 h, l;
            bf_split(av[4*q+0], h, l); vh.x = h; vl.x = l;
            bf_split(av[4*q+1], h, l); vh.y = h; vl.y = l;
            bf_split(av[4*q+2], h, l); vh.z = h; vl.z = l;
            bf_split(av[4*q+3], h, l); vh.w = h; vl.w = l;
            *reinterpret_cast<ushort4*>(&ch[base + 16*q]) = vh;
            *reinterpret_cast<ushort4*>(&cl[base + 16*q]) = vl;
        }
    }
}

// ---------------------------------------------------------------------------
// Kernel 3 (MFMA): fused = LN(x + ctx@Wo + bo) -> out.  LN in-register via
// 16-lane shfl_xor reductions.
// ---------------------------------------------------------------------------
__global__ __launch_bounds__(256, 2)
void k_out1(const u16* __restrict__ ch, const u16* __restrict__ cl,
            const u16* __restrict__ Wth, const u16* __restrict__ Wtl,
            const float* __restrict__ x, const float* __restrict__ bo,
            const float* __restrict__ ln_g, const float* __restrict__ ln_b,
            float* __restrict__ out)
{
    __shared__ u16 Ash[2][8192];
    __shared__ u16 Bsh[2][8192];

    const int tid = threadIdx.x;
    const int r0 = blockIdx.x * 128;
    const int c0 = blockIdx.y * 128;
    const u16* Wh = Wth + (size_t)3 * DM * DM;
    const u16* Wl = Wtl + (size_t)3 * DM * DM;

    const int lane = tid & 63, wid = tid >> 6;
    const int wm = wid >> 1, wn = wid & 1;
    const int fr = lane & 15, fg = lane >> 4;

    f32x4 acc[4][4];
    #pragma unroll
    for (int i = 0; i < 4; i++)
        #pragma unroll
        for (int j = 0; j < 4; j++) acc[i][j] = (f32x4){0.f,0.f,0.f,0.f};

    const int srow = tid >> 3;
    const int skc  = tid & 7;

    for (int k0 = 0; k0 < DM; k0 += 64) {
        __syncthreads();
        #pragma unroll
        for (int p = 0; p < 4; ++p) {
            const int row = srow + p*32;
            const int lo = skc*1024 + row*8;
            const int gr = r0 + row;
            uint4 vh = make_uint4(0u,0u,0u,0u), vl = vh;
            if (gr < MROWS) {
                const size_t ga = (size_t)gr*DM + k0 + skc*8;
                vh = *reinterpret_cast<const uint4*>(&ch[ga]);
                vl = *reinterpret_cast<const uint4*>(&cl[ga]);
            }
            *reinterpret_cast<uint4*>(&Ash[0][lo]) = vh;
            *reinterpret_cast<uint4*>(&Ash[1][lo]) = vl;
            const size_t gb = (size_t)(c0 + row)*DM + k0 + skc*8;
            *reinterpret_cast<uint4*>(&Bsh[0][lo]) = *reinterpret_cast<const uint4*>(&Wh[gb]);
            *reinterpret_cast<uint4*>(&Bsh[1][lo]) = *reinterpret_cast<const uint4*>(&Wl[gb]);
        }
        __syncthreads();
        #pragma unroll
        for (int ks = 0; ks < 2; ++ks) {
            const int kb = (ks*4 + fg) * 1024;
            bf16x8 ah[4], al[4], bh[4], blo[4];
            #pragma unroll
            for (int t = 0; t < 4; ++t) {
                const int ro = kb + (wm*64 + t*16 + fr)*8;
                ah[t] = *reinterpret_cast<const bf16x8*>(&Ash[0][ro]);
                al[t] = *reinterpret_cast<const bf16x8*>(&Ash[1][ro]);
                const int co = kb + (wn*64 + t*16 + fr)*8;
                bh[t]  = *reinterpret_cast<const bf16x8*>(&Bsh[0][co]);
                blo[t] = *reinterpret_cast<const bf16x8*>(&Bsh[1][co]);
            }
            #pragma unroll
            for (int mt = 0; mt < 4; ++mt)
                #pragma unroll
                for (int nt = 0; nt < 4; ++nt) {
                    acc[mt][nt] = __builtin_amdgcn_mfma_f32_16x16x32_bf16(ah[mt], bh[nt],  acc[mt][nt], 0,0,0);
                    acc[mt][nt] = __builtin_amdgcn_mfma_f32_16x16x32_bf16(al[mt], bh[nt],  acc[mt][nt], 0,0,0);
                    acc[mt][nt] = __builtin_amdgcn_mfma_f32_16x16x32_bf16(ah[mt], blo[nt], acc[mt][nt], 0,0,0);
                }
        }
    }

    // -------- epilogue: +bo +x, LayerNorm per 32-col group, store fused ----
    const float lgA = ln_g[fr],      lgB = ln_g[fr+16];
    const float lbA = ln_b[fr],      lbB = ln_b[fr+16];
    float bo_[4];
    #pragma unroll
    for (int nt = 0; nt < 4; ++nt) bo_[nt] = bo[c0 + wn*64 + nt*16 + fr];

    #pragma unroll
    for (int mt = 0; mt < 4; ++mt) {
        const int rbase = r0 + wm*64 + mt*16 + fg*4;
        #pragma unroll
        for (int g2 = 0; g2 < 2; ++g2) {
            const int ca = c0 + wn*64 + g2*32 + fr;
            const int cb = ca + 16;
            #pragma unroll
            for (int i = 0; i < 4; ++i) {
                const int rr = rbase + i;
                float ha = acc[mt][2*g2][i]   + bo_[2*g2];
                float hb = acc[mt][2*g2+1][i] + bo_[2*g2+1];
                if (rr < MROWS) {
                    ha += x[(size_t)rr*DM + ca];
                    hb += x[(size_t)rr*DM + cb];
                }
                float s = ha + hb;
                s += __shfl_xor(s, 1); s += __shfl_xor(s, 2);
                s += __shfl_xor(s, 4); s += __shfl_xor(s, 8);
                const float mu = s * 0.03125f;
                const float da = ha - mu, db = hb - mu;
                float v = da*da + db*db;
                v += __shfl_xor(v, 1); v += __shfl_xor(v, 2);
                v += __shfl_xor(v, 4); v += __shfl_xor(v, 8);
                const float rstd = 1.0f / sqrtf(v * 0.03125f + 1e-5f);
                if (rr < MROWS) {
                    out[(size_t)rr*DM + ca] = da * rstd * lgA + lbA;
                    out[(size_t)rr*DM + cb] = db * rstd * lgB + lbB;
                }
            }
        }
    }
}

// ---------------------------------------------------------------------------
// Kernel 4 (spill-fixed): out += gelu(out@W1 + b1)@W2 + b2.
// R7 post-mortem: full unroll of kq/oq loops hoisted 256 VGPRs of LDS loads
// -> spill (278 MB HBM/dispatch). Fix: `#pragma unroll 1` on the k-loops
// (live set ~60 VGPRs) + interleaved row mapping (r = tr + 16*i) so adjacent
// lanes hit adjacent LDS banks (stride 33 ≡ 1 bank), Ys padded to 67.
// ---------------------------------------------------------------------------
__global__ __launch_bounds__(256, 2)
void k_mlp(float* __restrict__ out,
           const float* __restrict__ W1, const float* __restrict__ b1,
           const float* __restrict__ W2, const float* __restrict__ b2)
{
    __shared__ float Fs[128*33];    // fused tile, pad 33
    __shared__ float Ys[128*67];    // gelu(y) tile, pad 67
    __shared__ float W1s[2048];     // [k][o] as given (32x64)
    __shared__ float W2s[2048];     // [o][c] as given (64x32)
    __shared__ float b1s[64];
    __shared__ float b2s[32];

    const int tid = threadIdx.x;
    const int gr0 = blockIdx.x * 128;          // 1125 blocks * 128 = 144000 exact

    // ---- stage weights + F tile
    for (int p = tid; p < 2048; p += 256) { W1s[p] = W1[p]; W2s[p] = W2[p]; }
    if (tid < 64) b1s[tid] = b1[tid];
    if (tid < 32) b2s[tid] = b2[tid];
    {
        const float* src = out + (size_t)gr0 * 32;
        #pragma unroll
        for (int p = 0; p < 4; ++p) {
            const int f4 = tid + p*256;        // 0..1023
            const int r = f4 >> 3, kq = f4 & 7;
            const float4 v = ld4(&src[f4*4]);
            Fs[r*33 + kq*4 + 0] = v.x;
            Fs[r*33 + kq*4 + 1] = v.y;
            Fs[r*33 + kq*4 + 2] = v.z;
            Fs[r*33 + kq*4 + 3] = v.w;
        }
    }
    __syncthreads();

    // ---- layer 1: Y = gelu(F @ W1 + b1); thread = rows {tr+16i}, cols tc*4
    {
        const int tr = tid >> 4;               // 0..15
        const int tc = tid & 15;               // 0..15
        const int c0m = tc*4;
        float y[8][4];
        const float4 bv = ld4(&b1s[c0m]);
        #pragma unroll
        for (int i = 0; i < 8; ++i) { y[i][0]=bv.x; y[i][1]=bv.y; y[i][2]=bv.z; y[i][3]=bv.w; }
        #pragma unroll 1
        for (int kq = 0; kq < 8; ++kq) {
            const float4 w0 = ld4(&W1s[(kq*4+0)*64 + c0m]);
            const float4 w1 = ld4(&W1s[(kq*4+1)*64 + c0m]);
            const float4 w2 = ld4(&W1s[(kq*4+2)*64 + c0m]);
            const float4 w3 = ld4(&W1s[(kq*4+3)*64 + c0m]);
            #pragma unroll
            for (int i = 0; i < 8; ++i) {
                const float4 a = ld4(&Fs[(tr + 16*i)*33 + kq*4]);
                y[i][0] = fmaf(a.x,w0.x, fmaf(a.y,w1.x, fmaf(a.z,w2.x, fmaf(a.w,w3.x, y[i][0]))));
                y[i][1] = fmaf(a.x,w0.y, fmaf(a.y,w1.y, fmaf(a.z,w2.y, fmaf(a.w,w3.y, y[i][1]))));
                y[i][2] = fmaf(a.x,w0.z, fmaf(a.y,w1.z, fmaf(a.z,w2.z, fmaf(a.w,w3.z, y[i][2]))));
                y[i][3] = fmaf(a.x,w0.w, fmaf(a.y,w1.w, fmaf(a.z,w2.w, fmaf(a.w,w3.w, y[i][3]))));
            }
        }
        #pragma unroll
        for (int i = 0; i < 8; ++i)
            #pragma unroll
            for (int j = 0; j < 4; ++j) {
                const float v = y[i][j];
                Ys[(tr + 16*i)*67 + c0m + j] = 0.5f * v * (1.0f + erff(v * GELU_K));
            }
    }
    __syncthreads();

    // ---- layer 2: out = F + (Y @ W2 + b2); thread = rows {tr2+32i}, cols tc2*4
    {
        const int tr2 = tid >> 3;              // 0..31
        const int tc2 = tid & 7;               // 0..7
        const int c2 = tc2*4;
        float z[4][4];
        const float4 bv = ld4(&b2s[c2]);
        #pragma unroll
        for (int i = 0; i < 4; ++i) { z[i][0]=bv.x; z[i][1]=bv.y; z[i][2]=bv.z; z[i][3]=bv.w; }
        #pragma unroll 1
        for (int oq = 0; oq < 16; ++oq) {
            const float4 w0 = ld4(&W2s[(oq*4+0)*32 + c2]);
            const float4 w1 = ld4(&W2s[(oq*4+1)*32 + c2]);
            const float4 w2 = ld4(&W2s[(oq*4+2)*32 + c2]);
            const float4 w3 = ld4(&W2s[(oq*4+3)*32 + c2]);
            #pragma unroll
            for (int i = 0; i < 4; ++i) {
                const float4 a = ld4(&Ys[(tr2 + 32*i)*67 + oq*4]);
                z[i][0] = fmaf(a.x,w0.x, fmaf(a.y,w1.x, fmaf(a.z,w2.x, fmaf(a.w,w3.x, z[i][0]))));
                z[i][1] = fmaf(a.x,w0.y, fmaf(a.y,w1.y, fmaf(a.z,w2.y, fmaf(a.w,w3.y, z[i][1]))));
                z[i][2] = fmaf(a.x,w0.z, fmaf(a.y,w1.z, fmaf(a.z,w2.z, fmaf(a.w,w3.z, z[i][2]))));
                z[i][3] = fmaf(a.x,w0.w, fmaf(a.y,w1.w, fmaf(a.z,w2.w, fmaf(a.w,w3.w, z[i][3]))));
            }
        }
        #pragma unroll
        for (int i = 0; i < 4; ++i) {
            const int row = tr2 + 32*i;
            const float* frow = &Fs[row*33 + c2];
            float4 v;
            v.x = frow[0] + z[i][0];
            v.y = frow[1] + z[i][1];
            v.z = frow[2] + z[i][2];
            v.w = frow[3] + z[i][3];
            st4(&out[((size_t)gr0 + row)*32 + c2], v);
        }
    }
}

// ---------------------------------------------------------------------------
extern "C" void kernel_launch(void* const* d_in, const int* in_sizes, int n_in,
                              void* d_out, int out_size, void* d_ws, size_t ws_size,
                              hipStream_t stream)
{
    const float* x   = (const float*)d_in[0];
    const int*   tk  = (const int*)  d_in[1];
    const float* Wq  = (const float*)d_in[2];
    const float* bq  = (const float*)d_in[3];
    const float* Wk  = (const float*)d_in[4];
    const float* bk  = (const float*)d_in[5];
    const float* Wv  = (const float*)d_in[6];
    const float* bv  = (const float*)d_in[7];
    const float* Wo  = (const float*)d_in[8];
    const float* bo  = (const float*)d_in[9];
    const float* lng = (const float*)d_in[10];
    const float* lnb = (const float*)d_in[11];
    const float* W1  = (const float*)d_in[12];
    const float* b1  = (const float*)d_in[13];
    const float* W2  = (const float*)d_in[14];
    const float* b2  = (const float*)d_in[15];
    float* out = (float*)d_out;

    // workspace layout (~76.3 MB):
    //   Qa/Ka/Va fp32 (55.3 MB) | xh/xl bf16 (18.4 MB, reused as ch/cl) |
    //   Wth/Wtl bf16 4 weights (2.4 MB)
    float* Qa = (float*)d_ws;
    float* Ka = Qa + (size_t)MROWS * DM;
    float* Va = Ka + (size_t)MROWS * DM;
    u16* xh  = (u16*)(Va + (size_t)MROWS * DM);
    u16* xl  = xh + (size_t)MROWS * DM;
    u16* Wth = xl + (size_t)MROWS * DM;
    u16* Wtl = Wth + (size_t)4 * DM * DM;
    u16* ch  = xh;   // reuse: xh/xl dead after k_qkvm
    u16* cl  = xl;

    k_convert<<<dim3(5076), 256, 0, stream>>>(x, Wq, Wk, Wv, Wo, xh, xl, Wth, Wtl);
    k_qkvm<<<dim3(94, 9), 256, 0, stream>>>(xh, xl, Wth, Wtl, bq, bk, bv, Qa, Ka, Va);
    k_attn<<<dim3(NTOK), 256, 0, stream>>>(Qa, Ka, Va, tk, ch, cl);
    k_out1<<<dim3(94, 3), 256, 0, stream>>>(ch, cl, Wth, Wtl, x, bo, lng, lnb, out);
    k_mlp<<<dim3(1125), 256, 0, stream>>>(out, W1, b1, W2, b2);
}